// Round 3
// baseline (1272.850 us; speedup 1.0000x reference)
//
#include <hip/hip_runtime.h>
#include <hip/hip_bf16.h>

typedef __attribute__((ext_vector_type(8))) short bf16x8;
typedef __attribute__((ext_vector_type(4))) unsigned short u16x4;
typedef __attribute__((ext_vector_type(4))) float f32x4;

constexpr int Bb = 4, Tt = 2048, Dd = 2048, Hh = 16, DHd = 128;

static __device__ __forceinline__ unsigned short f2bf(float f) {
  union { float f; unsigned u; } x; x.f = f;
  unsigned r = x.u + 0x7fffu + ((x.u >> 16) & 1u);
  return (unsigned short)(r >> 16);
}

// async global->LDS, 16B per lane (dest = wave-uniform base + lane*16)
static __device__ __forceinline__ void gld16(const void* g, void* l) {
  __builtin_amdgcn_global_load_lds(
      (__attribute__((address_space(1))) void*)g,
      (__attribute__((address_space(3))) void*)l, 16, 0, 0);
}

// ---------------------------------------------------------------------------
// fp32 -> bf16 bulk convert (8 elems/thread)
// ---------------------------------------------------------------------------
__global__ __launch_bounds__(256) void cvt_bf16(const float* __restrict__ s,
                                                unsigned short* __restrict__ d) {
  const size_t i = ((size_t)blockIdx.x * 256 + threadIdx.x) * 8;
  float4 a = *(const float4*)(s + i);
  float4 b = *(const float4*)(s + i + 4);
  bf16x8 pk;
  pk[0] = (short)f2bf(a.x); pk[1] = (short)f2bf(a.y);
  pk[2] = (short)f2bf(a.z); pk[3] = (short)f2bf(a.w);
  pk[4] = (short)f2bf(b.x); pk[5] = (short)f2bf(b.y);
  pk[6] = (short)f2bf(b.z); pk[7] = (short)f2bf(b.w);
  *(bf16x8*)(d + i) = pk;
}

// ---------------------------------------------------------------------------
// Weight transpose + fp32->bf16 convert: W[k][n] -> Wt[n][k]
// ---------------------------------------------------------------------------
__global__ __launch_bounds__(256) void wtrans_all(
    const float* __restrict__ Wq, const float* __restrict__ Wk,
    const float* __restrict__ Wv, const float* __restrict__ Wo,
    unsigned short* __restrict__ WqT, unsigned short* __restrict__ WkT,
    unsigned short* __restrict__ WvT, unsigned short* __restrict__ WoT,
    float qscale) {
  __shared__ __align__(16) unsigned short tile[64][72];
  const float* src;
  unsigned short* dst;
  float sc = 1.0f;
  switch (blockIdx.z) {
    case 0: src = Wq; dst = WqT; sc = qscale; break;
    case 1: src = Wk; dst = WkT; break;
    case 2: src = Wv; dst = WvT; break;
    default: src = Wo; dst = WoT; break;
  }
  const int t = threadIdx.x;
  const int k0 = blockIdx.x * 64, n0 = blockIdx.y * 64;
  const int c = t & 15, r = t >> 4;
#pragma unroll
  for (int p = 0; p < 4; ++p) {
    const int rr = r + 16 * p;
    float4 v = *(const float4*)(src + (size_t)(k0 + rr) * Dd + n0 + c * 4);
    u16x4 pk;
    pk[0] = f2bf(v.x * sc); pk[1] = f2bf(v.y * sc);
    pk[2] = f2bf(v.z * sc); pk[3] = f2bf(v.w * sc);
    *(u16x4*)&tile[rr][c * 4] = pk;
  }
  __syncthreads();
#pragma unroll
  for (int p = 0; p < 4; ++p) {
    const int nn = r + 16 * p;
    u16x4 pk;
    pk[0] = tile[c * 4 + 0][nn]; pk[1] = tile[c * 4 + 1][nn];
    pk[2] = tile[c * 4 + 2][nn]; pk[3] = tile[c * 4 + 3][nn];
    *(u16x4*)(dst + (size_t)(n0 + nn) * Dd + k0 + c * 4) = pk;
  }
}

// ---------------------------------------------------------------------------
// GEMM: out[8192][2048] = A[8192][2048](bf16) * Bt[2048][2048]^T (bf16)
// m97 structure: 128x128 tile, BK=64, global_load_lds width-16, linear LDS.
// OMODE: 0 = fp32 flat [M][N]; 1 = bf16 [B,H,T,dh]; 2 = bf16 [B,H,dh,T]
// ---------------------------------------------------------------------------
template <int OMODE>
__global__ __launch_bounds__(256, 2) void gemm_bt(
    const unsigned short* __restrict__ A, const unsigned short* __restrict__ Bt,
    void* __restrict__ Outp) {
  __shared__ __align__(16) unsigned short As[128 * 64];
  __shared__ __align__(16) unsigned short Bs[128 * 64];
  const int t = threadIdx.x;
  const int lane = t & 63, w = t >> 6;
  const int wr = w >> 1, wc = w & 1;
  const int fr = lane & 15, fq = lane >> 4;
  const int m0 = blockIdx.x * 128, n0 = blockIdx.y * 128;
  const int srow = t >> 3, scol = (t & 7) * 8;
  const unsigned short* Ag = A + (size_t)(m0 + srow) * Dd + scol;
  const unsigned short* Bg = Bt + (size_t)(n0 + srow) * Dd + scol;
  unsigned short* Asl = As + t * 8;
  unsigned short* Bsl = Bs + t * 8;

  f32x4 acc[4][4] = {};

  for (int k0 = 0; k0 < Dd; k0 += 64) {
#pragma unroll
    for (int i = 0; i < 4; ++i) {
      gld16(Ag + (size_t)i * 32 * Dd + k0, Asl + i * 2048);
      gld16(Bg + (size_t)i * 32 * Dd + k0, Bsl + i * 2048);
    }
    __syncthreads();
#pragma unroll
    for (int ks = 0; ks < 2; ++ks) {
      bf16x8 af[4], bfr[4];
#pragma unroll
      for (int m = 0; m < 4; ++m)
        af[m] = *(const bf16x8*)&As[(wr * 64 + m * 16 + fr) * 64 + ks * 32 + fq * 8];
#pragma unroll
      for (int n = 0; n < 4; ++n)
        bfr[n] = *(const bf16x8*)&Bs[(wc * 64 + n * 16 + fr) * 64 + ks * 32 + fq * 8];
#pragma unroll
      for (int m = 0; m < 4; ++m)
#pragma unroll
        for (int n = 0; n < 4; ++n)
          acc[m][n] = __builtin_amdgcn_mfma_f32_16x16x32_bf16(
              af[m], bfr[n], acc[m][n], 0, 0, 0);
    }
    __syncthreads();
  }

#pragma unroll
  for (int m = 0; m < 4; ++m) {
    const int mg = m0 + wr * 64 + m * 16 + fq * 4;
    const int bb = mg >> 11, tt0 = mg & (Tt - 1);
#pragma unroll
    for (int n = 0; n < 4; ++n) {
      const int ng = n0 + wc * 64 + n * 16 + fr;
      if (OMODE == 0) {
        float* o = (float*)Outp + (size_t)mg * Dd + ng;
#pragma unroll
        for (int r = 0; r < 4; ++r) o[(size_t)r * Dd] = acc[m][n][r];
      } else if (OMODE == 1) {
        const int h = ng >> 7, dh = ng & 127;
        unsigned short* o = (unsigned short*)Outp +
                            (((size_t)bb * Hh + h) * Tt + tt0) * DHd + dh;
#pragma unroll
        for (int r = 0; r < 4; ++r) o[r * DHd] = f2bf(acc[m][n][r]);
      } else {
        const int h = ng >> 7, dh = ng & 127;
        u16x4 pk;
#pragma unroll
        for (int r = 0; r < 4; ++r) pk[r] = f2bf(acc[m][n][r]);
        *(u16x4*)((unsigned short*)Outp +
                  (((size_t)bb * Hh + h) * DHd + dh) * Tt + tt0) = pk;
      }
    }
  }
}

// ---------------------------------------------------------------------------
// Causal flash attention — BARRIER-FREE. Each wave owns a 16-row q-tile and
// reads K/V fragments directly from global (L1/L2-resident); no K/V LDS, no
// __syncthreads. S^T = mfma(K,Q) so softmax state is per-lane scalar (q=fr).
// Scores are in exp2 domain (log2e folded into Wq). Per-wave P LDS roundtrip.
// Q,K: [B,H,T,128] bf16; V: [B,H,128,T] bf16; Out: [B,T,2048] bf16.
// ---------------------------------------------------------------------------
__global__ __launch_bounds__(256, 3) void fattn(
    const unsigned short* __restrict__ Qp, const unsigned short* __restrict__ Kp,
    const unsigned short* __restrict__ Vt, unsigned short* __restrict__ Ao) {
  __shared__ __align__(16) unsigned short Ps[4][16][72];  // per-wave P[q16][kv64]
  const int t = threadIdx.x, lane = t & 63, w = t >> 6;
  const int fr = lane & 15, fq = lane >> 4;
  const int qb = gridDim.x - 1 - blockIdx.x;  // heaviest blocks first
  const int q0 = qb * 64 + w * 16;            // this wave's 16 q-rows
  const int bh = blockIdx.y;
  const unsigned short* Qb = Qp + (size_t)bh * Tt * DHd;
  const unsigned short* Kb = Kp + (size_t)bh * Tt * DHd;
  const unsigned short* Vb = Vt + (size_t)bh * DHd * Tt;

  bf16x8 qf[4];
#pragma unroll
  for (int ks = 0; ks < 4; ++ks)
    qf[ks] = *(const bf16x8*)(Qb + (size_t)(q0 + fr) * DHd + ks * 32 + fq * 8);

  f32x4 oacc[8] = {};
  float m_ = -1e30f, l_ = 0.f;

  const int ntile = qb + 1;
  for (int kt = 0; kt < ntile; ++kt) {
    const int kv0 = kt * 64;

    // S^T = K·Q^T : lane holds S[kv = tt*16+fq*4+r][q = fr]
    f32x4 s[4] = {};
    __builtin_amdgcn_s_setprio(1);
#pragma unroll
    for (int tt = 0; tt < 4; ++tt) {
      bf16x8 kf[4];
#pragma unroll
      for (int ks = 0; ks < 4; ++ks)
        kf[ks] = *(const bf16x8*)(Kb + (size_t)(kv0 + tt * 16 + fr) * DHd +
                                  ks * 32 + fq * 8);
#pragma unroll
      for (int ks = 0; ks < 4; ++ks)
        s[tt] = __builtin_amdgcn_mfma_f32_16x16x32_bf16(kf[ks], qf[ks], s[tt], 0, 0, 0);
    }
    __builtin_amdgcn_s_setprio(0);

    if (kt == ntile - 1) {  // diagonal tile: causal mask
#pragma unroll
      for (int tt = 0; tt < 4; ++tt)
#pragma unroll
        for (int r = 0; r < 4; ++r)
          if (tt * 16 + fq * 4 + r > (w & 3) * 16 + fr) s[tt][r] = -1e30f;
    }

    // online softmax in exp2 domain, per-lane scalar state (q = fr)
    float tmax = s[0][0];
#pragma unroll
    for (int tt = 0; tt < 4; ++tt)
#pragma unroll
      for (int r = 0; r < 4; ++r) tmax = fmaxf(tmax, s[tt][r]);
    tmax = fmaxf(tmax, __shfl_xor(tmax, 16));
    tmax = fmaxf(tmax, __shfl_xor(tmax, 32));

    if (!__all(tmax <= m_ + 8.0f)) {  // defer-max (T13): rescale only on growth
      const float mn = fmaxf(m_, tmax);
      const float alpha = __builtin_amdgcn_exp2f(m_ - mn);
      m_ = mn;
      float al4[4];
#pragma unroll
      for (int r = 0; r < 4; ++r) al4[r] = __shfl(alpha, fq * 4 + r);
#pragma unroll
      for (int dt = 0; dt < 8; ++dt)
#pragma unroll
        for (int r = 0; r < 4; ++r) oacc[dt][r] *= al4[r];
      l_ *= alpha;
    }

    float rs = 0.f;
#pragma unroll
    for (int tt = 0; tt < 4; ++tt)
#pragma unroll
      for (int r = 0; r < 4; ++r) {
        const float p = __builtin_amdgcn_exp2f(s[tt][r] - m_);
        s[tt][r] = p;
        rs += p;
      }
    rs += __shfl_xor(rs, 16);
    rs += __shfl_xor(rs, 32);
    l_ += rs;

    // P^T -> Ps[q][kv] via v_cvt_pk_bf16_f32 (per-wave private: no barrier)
#pragma unroll
    for (int tt = 0; tt < 4; ++tt) {
      unsigned r0, r1;
      asm("v_cvt_pk_bf16_f32 %0, %1, %2" : "=v"(r0) : "v"(s[tt][0]), "v"(s[tt][1]));
      asm("v_cvt_pk_bf16_f32 %0, %1, %2" : "=v"(r1) : "v"(s[tt][2]), "v"(s[tt][3]));
      uint2 pk = {r0, r1};
      *(uint2*)&Ps[w][fr][tt * 16 + fq * 4] = pk;
    }

    // PV: oacc[dt] = out[q=fq*4+r][dv=dt*16+fr], V fragments direct from global
    __builtin_amdgcn_s_setprio(1);
#pragma unroll
    for (int ks2 = 0; ks2 < 2; ++ks2) {
      const bf16x8 pf = *(const bf16x8*)&Ps[w][fr][ks2 * 32 + fq * 8];
#pragma unroll
      for (int dt = 0; dt < 8; ++dt) {
        const bf16x8 vf = *(const bf16x8*)(Vb + (size_t)(dt * 16 + fr) * Tt +
                                           kv0 + ks2 * 32 + fq * 8);
        oacc[dt] = __builtin_amdgcn_mfma_f32_16x16x32_bf16(pf, vf, oacc[dt], 0, 0, 0);
      }
    }
    __builtin_amdgcn_s_setprio(0);
  }

  const int bb = bh >> 4, hh = bh & 15;
  float linv[4];
#pragma unroll
  for (int r = 0; r < 4; ++r) linv[r] = 1.0f / __shfl(l_, fq * 4 + r);
  const int qrow = (qb * 64 + w * 16) + fq * 4;
#pragma unroll
  for (int r = 0; r < 4; ++r) {
    unsigned short* o = Ao + ((size_t)bb * Tt + qrow + r) * Dd + hh * DHd + fr;
#pragma unroll
    for (int dt = 0; dt < 8; ++dt) o[dt * 16] = f2bf(oacc[dt][r] * linv[r]);
  }
}

// ---------------------------------------------------------------------------
extern "C" void kernel_launch(void* const* d_in, const int* in_sizes, int n_in,
                              void* d_out, int out_size, void* d_ws, size_t ws_size,
                              hipStream_t stream) {
  const float* q = (const float*)d_in[0];
  const float* k = (const float*)d_in[1];
  const float* v = (const float*)d_in[2];
  // d_in[3] = mask (known causal tril; unused)
  const float* Wq = (const float*)d_in[4];
  const float* Wk = (const float*)d_in[5];
  const float* Wv = (const float*)d_in[6];
  const float* Wo = (const float*)d_in[7];

  const size_t WE = (size_t)Dd * Dd;
  const size_t PE = (size_t)Bb * Hh * Tt * DHd;
  unsigned short* WqT = (unsigned short*)d_ws;
  unsigned short* WkT = WqT + WE;
  unsigned short* WvT = WkT + WE;
  unsigned short* WoT = WvT + WE;
  unsigned short* Qx = WoT + WE;  // [B,H,T,dh]
  unsigned short* Kx = Qx + PE;   // [B,H,T,dh]
  unsigned short* Vx = Kx + PE;   // [B,H,dh,T]
  unsigned short* Ax = Vx + PE;   // bf16 staging, then attn out [B,T,H*dh]

  // scores in exp2 domain: fold log2(e)/sqrt(dk) into Wq
  const float qscale = (float)(1.4426950408889634 / 11.313708498984761);
  wtrans_all<<<dim3(32, 32, 4), 256, 0, stream>>>(
      Wq, Wk, Wv, Wo, WqT, WkT, WvT, WoT, qscale);

  cvt_bf16<<<dim3(8192), 256, 0, stream>>>(q, Ax);
  gemm_bt<1><<<dim3(64, 16), 256, 0, stream>>>(Ax, WqT, Qx);
  cvt_bf16<<<dim3(8192), 256, 0, stream>>>(k, Ax);
  gemm_bt<1><<<dim3(64, 16), 256, 0, stream>>>(Ax, WkT, Kx);
  cvt_bf16<<<dim3(8192), 256, 0, stream>>>(v, Ax);
  gemm_bt<2><<<dim3(64, 16), 256, 0, stream>>>(Ax, WvT, Vx);
  fattn<<<dim3(Tt / 64, Bb * Hh), 256, 0, stream>>>(Qx, Kx, Vx, Ax);
  gemm_bt<0><<<dim3(64, 16), 256, 0, stream>>>(Ax, WoT, (float*)d_out);
}

// Round 4
// 614.327 us; speedup vs baseline: 2.0719x; 2.0719x over previous
//
#include <hip/hip_runtime.h>
#include <hip/hip_bf16.h>

typedef __attribute__((ext_vector_type(8))) short bf16x8;
typedef __attribute__((ext_vector_type(4))) unsigned short u16x4;
typedef __attribute__((ext_vector_type(4))) float f32x4;

constexpr int Bb = 4, Tt = 2048, Dd = 2048, Hh = 16, DHd = 128;

static __device__ __forceinline__ unsigned short f2bf(float f) {
  union { float f; unsigned u; } x; x.f = f;
  unsigned r = x.u + 0x7fffu + ((x.u >> 16) & 1u);
  return (unsigned short)(r >> 16);
}

// async global->LDS, 16B per lane (dest = wave-uniform base + lane*16)
static __device__ __forceinline__ void gld16(const void* g, void* l) {
  __builtin_amdgcn_global_load_lds(
      (__attribute__((address_space(1))) void*)g,
      (__attribute__((address_space(3))) void*)l, 16, 0, 0);
}

// ---------------------------------------------------------------------------
// fp32 -> bf16 bulk convert (8 elems/thread)
// ---------------------------------------------------------------------------
__global__ __launch_bounds__(256) void cvt_bf16(const float* __restrict__ s,
                                                unsigned short* __restrict__ d) {
  const size_t i = ((size_t)blockIdx.x * 256 + threadIdx.x) * 8;
  float4 a = *(const float4*)(s + i);
  float4 b = *(const float4*)(s + i + 4);
  bf16x8 pk;
  pk[0] = (short)f2bf(a.x); pk[1] = (short)f2bf(a.y);
  pk[2] = (short)f2bf(a.z); pk[3] = (short)f2bf(a.w);
  pk[4] = (short)f2bf(b.x); pk[5] = (short)f2bf(b.y);
  pk[6] = (short)f2bf(b.z); pk[7] = (short)f2bf(b.w);
  *(bf16x8*)(d + i) = pk;
}

// ---------------------------------------------------------------------------
// Weight transpose + fp32->bf16 convert: W[k][n] -> Wt[n][k]
// ---------------------------------------------------------------------------
__global__ __launch_bounds__(256) void wtrans_all(
    const float* __restrict__ Wq, const float* __restrict__ Wk,
    const float* __restrict__ Wv, const float* __restrict__ Wo,
    unsigned short* __restrict__ WqT, unsigned short* __restrict__ WkT,
    unsigned short* __restrict__ WvT, unsigned short* __restrict__ WoT,
    float qscale) {
  __shared__ __align__(16) unsigned short tile[64][72];
  const float* src;
  unsigned short* dst;
  float sc = 1.0f;
  switch (blockIdx.z) {
    case 0: src = Wq; dst = WqT; sc = qscale; break;
    case 1: src = Wk; dst = WkT; break;
    case 2: src = Wv; dst = WvT; break;
    default: src = Wo; dst = WoT; break;
  }
  const int t = threadIdx.x;
  const int k0 = blockIdx.x * 64, n0 = blockIdx.y * 64;
  const int c = t & 15, r = t >> 4;
#pragma unroll
  for (int p = 0; p < 4; ++p) {
    const int rr = r + 16 * p;
    float4 v = *(const float4*)(src + (size_t)(k0 + rr) * Dd + n0 + c * 4);
    u16x4 pk;
    pk[0] = f2bf(v.x * sc); pk[1] = f2bf(v.y * sc);
    pk[2] = f2bf(v.z * sc); pk[3] = f2bf(v.w * sc);
    *(u16x4*)&tile[rr][c * 4] = pk;
  }
  __syncthreads();
#pragma unroll
  for (int p = 0; p < 4; ++p) {
    const int nn = r + 16 * p;
    u16x4 pk;
    pk[0] = tile[c * 4 + 0][nn]; pk[1] = tile[c * 4 + 1][nn];
    pk[2] = tile[c * 4 + 2][nn]; pk[3] = tile[c * 4 + 3][nn];
    *(u16x4*)(dst + (size_t)(n0 + nn) * Dd + k0 + c * 4) = pk;
  }
}

// ---------------------------------------------------------------------------
// GEMM: out[8192][2048] = A[8192][2048](bf16) * Bt[2048][2048]^T (bf16)
// m97 structure: 128x128 tile, BK=64, global_load_lds width-16, linear LDS.
// OMODE: 0 = fp32 flat [M][N]; 1 = bf16 [B,H,T,dh]; 2 = bf16 [B,H,dh,T]
// ---------------------------------------------------------------------------
template <int OMODE>
__global__ __launch_bounds__(256, 2) void gemm_bt(
    const unsigned short* __restrict__ A, const unsigned short* __restrict__ Bt,
    void* __restrict__ Outp) {
  __shared__ __align__(16) unsigned short As[128 * 64];
  __shared__ __align__(16) unsigned short Bs[128 * 64];
  const int t = threadIdx.x;
  const int lane = t & 63, w = t >> 6;
  const int wr = w >> 1, wc = w & 1;
  const int fr = lane & 15, fq = lane >> 4;
  const int m0 = blockIdx.x * 128, n0 = blockIdx.y * 128;
  const int srow = t >> 3, scol = (t & 7) * 8;
  const unsigned short* Ag = A + (size_t)(m0 + srow) * Dd + scol;
  const unsigned short* Bg = Bt + (size_t)(n0 + srow) * Dd + scol;
  unsigned short* Asl = As + t * 8;
  unsigned short* Bsl = Bs + t * 8;

  f32x4 acc[4][4] = {};

  for (int k0 = 0; k0 < Dd; k0 += 64) {
#pragma unroll
    for (int i = 0; i < 4; ++i) {
      gld16(Ag + (size_t)i * 32 * Dd + k0, Asl + i * 2048);
      gld16(Bg + (size_t)i * 32 * Dd + k0, Bsl + i * 2048);
    }
    __syncthreads();
#pragma unroll
    for (int ks = 0; ks < 2; ++ks) {
      bf16x8 af[4], bfr[4];
#pragma unroll
      for (int m = 0; m < 4; ++m)
        af[m] = *(const bf16x8*)&As[(wr * 64 + m * 16 + fr) * 64 + ks * 32 + fq * 8];
#pragma unroll
      for (int n = 0; n < 4; ++n)
        bfr[n] = *(const bf16x8*)&Bs[(wc * 64 + n * 16 + fr) * 64 + ks * 32 + fq * 8];
#pragma unroll
      for (int m = 0; m < 4; ++m)
#pragma unroll
        for (int n = 0; n < 4; ++n)
          acc[m][n] = __builtin_amdgcn_mfma_f32_16x16x32_bf16(
              af[m], bfr[n], acc[m][n], 0, 0, 0);
    }
    __syncthreads();
  }

#pragma unroll
  for (int m = 0; m < 4; ++m) {
    const int mg = m0 + wr * 64 + m * 16 + fq * 4;
    const int bb = mg >> 11, tt0 = mg & (Tt - 1);
#pragma unroll
    for (int n = 0; n < 4; ++n) {
      const int ng = n0 + wc * 64 + n * 16 + fr;
      if (OMODE == 0) {
        float* o = (float*)Outp + (size_t)mg * Dd + ng;
#pragma unroll
        for (int r = 0; r < 4; ++r) o[(size_t)r * Dd] = acc[m][n][r];
      } else if (OMODE == 1) {
        const int h = ng >> 7, dh = ng & 127;
        unsigned short* o = (unsigned short*)Outp +
                            (((size_t)bb * Hh + h) * Tt + tt0) * DHd + dh;
#pragma unroll
        for (int r = 0; r < 4; ++r) o[r * DHd] = f2bf(acc[m][n][r]);
      } else {
        const int h = ng >> 7, dh = ng & 127;
        u16x4 pk;
#pragma unroll
        for (int r = 0; r < 4; ++r) pk[r] = f2bf(acc[m][n][r]);
        *(u16x4*)((unsigned short*)Outp +
                  (((size_t)bb * Hh + h) * DHd + dh) * Tt + tt0) = pk;
      }
    }
  }
}

// ---------------------------------------------------------------------------
// Causal flash attention. QBLK=64 (4 waves x 16 q-rows), KVBLK=64.
// K/V double-buffered in LDS via async global_load_lds (width 16), counted
// vmcnt(8): tile t+1's loads fly under tile t's compute. LDS is XOR-swizzled
// (chunk ^= row&7) via pre-swizzled GLOBAL source (gld_lds dest stays linear)
// so the b128 fragment reads are ~2-way (free) instead of 16-way.
// S^T = mfma(K,Q): softmax state is per-lane scalar (q = fr). exp2 domain
// (log2e folded into Wq), defer-max (T13), cvt_pk P pack, setprio on MFMA.
// Q,K: [B,H,T,128] bf16; V: [B,H,128,T] bf16; Out: [B,T,2048] bf16.
// ---------------------------------------------------------------------------
__global__ __launch_bounds__(256, 2) void fattn(
    const unsigned short* __restrict__ Qp, const unsigned short* __restrict__ Kp,
    const unsigned short* __restrict__ Vt, unsigned short* __restrict__ Ao) {
  __shared__ __align__(16) unsigned short Ks[2][64 * 128];   // K[kv][dh], swizzled
  __shared__ __align__(16) unsigned short Vs[2][128 * 64];   // V^T[dv][kv], swizzled
  __shared__ __align__(16) unsigned short Ps[4][16][72];     // per-wave P[q16][kv64]
  const int t = threadIdx.x, lane = t & 63, w = t >> 6;
  const int fr = lane & 15, fq = lane >> 4;
  const int rsw = fr & 7;  // read-side swizzle key (row & 7, rows stride 16)
  const int qb = gridDim.x - 1 - blockIdx.x;  // heaviest blocks first
  const int q0 = qb * 64 + w * 16;            // this wave's 16 q-rows
  const int bh = blockIdx.y;
  const unsigned short* Qb = Qp + (size_t)bh * Tt * DHd;
  const unsigned short* Kb = Kp + (size_t)bh * Tt * DHd;
  const unsigned short* Vb = Vt + (size_t)bh * DHd * Tt;

  bf16x8 qf[4];
#pragma unroll
  for (int ks = 0; ks < 4; ++ks)
    qf[ks] = *(const bf16x8*)(Qb + (size_t)(q0 + fr) * DHd + ks * 32 + fq * 8);

  f32x4 oacc[8] = {};
  float m_ = -1e30f, l_ = 0.f;

  // stage tile kv0 into buffer b: source chunk pre-swizzled (chunk ^ row&7)
  auto STAGE = [&](int b, int kv0) {
#pragma unroll
    for (int p = 0; p < 4; ++p) {  // K: 64 rows x 16 chunks of 16B
      const int idx = t + p * 256, row = idx >> 4, ch = idx & 15;
      gld16(Kb + (size_t)(kv0 + row) * DHd + ((ch ^ (row & 7)) * 8),
            &Ks[b][idx * 8]);
    }
#pragma unroll
    for (int p = 0; p < 4; ++p) {  // V: 128 rows x 8 chunks of 16B
      const int idx = t + p * 256, row = idx >> 3, ch = idx & 7;
      gld16(Vb + (size_t)row * Tt + kv0 + ((ch ^ (row & 7)) * 8),
            &Vs[b][idx * 8]);
    }
  };

  const int ntile = qb + 1;
  STAGE(0, 0);
  int cur = 0;

  for (int kt = 0; kt < ntile; ++kt) {
    __builtin_amdgcn_s_barrier();  // all waves done reading buf[cur^1]
    if (kt + 1 < ntile) {
      STAGE(cur ^ 1, (kt + 1) * 64);
      asm volatile("s_waitcnt vmcnt(8)" ::: "memory");  // tile kt's 8 landed
    } else {
      asm volatile("s_waitcnt vmcnt(0)" ::: "memory");
    }
    __builtin_amdgcn_sched_barrier(0);
    __builtin_amdgcn_s_barrier();  // buf[cur] visible to all waves
    const unsigned short* Kc = &Ks[cur][0];
    const unsigned short* Vc = &Vs[cur][0];

    // S^T = K·Q^T : lane holds S[kv = tt*16+fq*4+r][q = fr]
    f32x4 s[4] = {};
    __builtin_amdgcn_s_setprio(1);
#pragma unroll
    for (int tt = 0; tt < 4; ++tt) {
      bf16x8 kf[4];
#pragma unroll
      for (int ks = 0; ks < 4; ++ks)
        kf[ks] = *(const bf16x8*)(Kc + (tt * 16 + fr) * 128 +
                                  ((ks * 4 + fq) ^ rsw) * 8);
#pragma unroll
      for (int ks = 0; ks < 4; ++ks)
        s[tt] = __builtin_amdgcn_mfma_f32_16x16x32_bf16(kf[ks], qf[ks], s[tt], 0, 0, 0);
    }
    __builtin_amdgcn_s_setprio(0);

    if (kt == ntile - 1) {  // diagonal tile: causal mask
#pragma unroll
      for (int tt = 0; tt < 4; ++tt)
#pragma unroll
        for (int r = 0; r < 4; ++r)
          if (tt * 16 + fq * 4 + r > w * 16 + fr) s[tt][r] = -1e30f;
    }

    // online softmax in exp2 domain, per-lane scalar state (q = fr)
    float tmax = s[0][0];
#pragma unroll
    for (int tt = 0; tt < 4; ++tt)
#pragma unroll
      for (int r = 0; r < 4; ++r) tmax = fmaxf(tmax, s[tt][r]);
    tmax = fmaxf(tmax, __shfl_xor(tmax, 16));
    tmax = fmaxf(tmax, __shfl_xor(tmax, 32));

    if (!__all(tmax <= m_ + 8.0f)) {  // defer-max: rescale only on growth
      const float mn = fmaxf(m_, tmax);
      const float alpha = __builtin_amdgcn_exp2f(m_ - mn);
      m_ = mn;
      float al4[4];
#pragma unroll
      for (int r = 0; r < 4; ++r) al4[r] = __shfl(alpha, fq * 4 + r);
#pragma unroll
      for (int dt = 0; dt < 8; ++dt)
#pragma unroll
        for (int r = 0; r < 4; ++r) oacc[dt][r] *= al4[r];
      l_ *= alpha;
    }

    float rs = 0.f;
#pragma unroll
    for (int tt = 0; tt < 4; ++tt)
#pragma unroll
      for (int r = 0; r < 4; ++r) {
        const float p = __builtin_amdgcn_exp2f(s[tt][r] - m_);
        s[tt][r] = p;
        rs += p;
      }
    rs += __shfl_xor(rs, 16);
    rs += __shfl_xor(rs, 32);
    l_ += rs;

    // P^T -> Ps[q][kv] via v_cvt_pk_bf16_f32 (per-wave private: no barrier)
#pragma unroll
    for (int tt = 0; tt < 4; ++tt) {
      unsigned r0, r1;
      asm("v_cvt_pk_bf16_f32 %0, %1, %2" : "=v"(r0) : "v"(s[tt][0]), "v"(s[tt][1]));
      asm("v_cvt_pk_bf16_f32 %0, %1, %2" : "=v"(r1) : "v"(s[tt][2]), "v"(s[tt][3]));
      uint2 pk = {r0, r1};
      *(uint2*)&Ps[w][fr][tt * 16 + fq * 4] = pk;
    }

    // PV: oacc[dt] = out[q=fq*4+r][dv=dt*16+fr]
    __builtin_amdgcn_s_setprio(1);
#pragma unroll
    for (int ks2 = 0; ks2 < 2; ++ks2) {
      const bf16x8 pf = *(const bf16x8*)&Ps[w][fr][ks2 * 32 + fq * 8];
#pragma unroll
      for (int dt = 0; dt < 8; ++dt) {
        const bf16x8 vf = *(const bf16x8*)(Vc + (dt * 16 + fr) * 64 +
                                           ((ks2 * 4 + fq) ^ rsw) * 8);
        oacc[dt] = __builtin_amdgcn_mfma_f32_16x16x32_bf16(pf, vf, oacc[dt], 0, 0, 0);
      }
    }
    __builtin_amdgcn_s_setprio(0);
    cur ^= 1;
  }

  const int bb = bh >> 4, hh = bh & 15;
  float linv[4];
#pragma unroll
  for (int r = 0; r < 4; ++r) linv[r] = 1.0f / __shfl(l_, fq * 4 + r);
  const int qrow = qb * 64 + w * 16 + fq * 4;
#pragma unroll
  for (int r = 0; r < 4; ++r) {
    unsigned short* o = Ao + ((size_t)bb * Tt + qrow + r) * Dd + hh * DHd + fr;
#pragma unroll
    for (int dt = 0; dt < 8; ++dt) o[dt * 16] = f2bf(oacc[dt][r] * linv[r]);
  }
}

// ---------------------------------------------------------------------------
extern "C" void kernel_launch(void* const* d_in, const int* in_sizes, int n_in,
                              void* d_out, int out_size, void* d_ws, size_t ws_size,
                              hipStream_t stream) {
  const float* q = (const float*)d_in[0];
  const float* k = (const float*)d_in[1];
  const float* v = (const float*)d_in[2];
  // d_in[3] = mask (known causal tril; unused)
  const float* Wq = (const float*)d_in[4];
  const float* Wk = (const float*)d_in[5];
  const float* Wv = (const float*)d_in[6];
  const float* Wo = (const float*)d_in[7];

  const size_t WE = (size_t)Dd * Dd;
  const size_t PE = (size_t)Bb * Hh * Tt * DHd;
  unsigned short* WqT = (unsigned short*)d_ws;
  unsigned short* WkT = WqT + WE;
  unsigned short* WvT = WkT + WE;
  unsigned short* WoT = WvT + WE;
  unsigned short* Qx = WoT + WE;  // [B,H,T,dh]
  unsigned short* Kx = Qx + PE;   // [B,H,T,dh]
  unsigned short* Vx = Kx + PE;   // [B,H,dh,T]
  unsigned short* Ax = Vx + PE;   // bf16 staging, then attn out [B,T,H*dh]

  // scores in exp2 domain: fold log2(e)/sqrt(dk) into Wq
  const float qscale = (float)(1.4426950408889634 / 11.313708498984761);
  wtrans_all<<<dim3(32, 32, 4), 256, 0, stream>>>(
      Wq, Wk, Wv, Wo, WqT, WkT, WvT, WoT, qscale);

  cvt_bf16<<<dim3(8192), 256, 0, stream>>>(q, Ax);
  gemm_bt<1><<<dim3(64, 16), 256, 0, stream>>>(Ax, WqT, Qx);
  cvt_bf16<<<dim3(8192), 256, 0, stream>>>(k, Ax);
  gemm_bt<1><<<dim3(64, 16), 256, 0, stream>>>(Ax, WkT, Kx);
  cvt_bf16<<<dim3(8192), 256, 0, stream>>>(v, Ax);
  gemm_bt<2><<<dim3(64, 16), 256, 0, stream>>>(Ax, WvT, Vx);
  fattn<<<dim3(Tt / 64, Bb * Hh), 256, 0, stream>>>(Qx, Kx, Vx, Ax);
  gemm_bt<0><<<dim3(64, 16), 256, 0, stream>>>(Ax, WoT, (float*)d_out);
}

// Round 5
// 548.175 us; speedup vs baseline: 2.3220x; 1.1207x over previous
//
#include <hip/hip_runtime.h>
#include <hip/hip_bf16.h>

typedef __attribute__((ext_vector_type(8))) short bf16x8;
typedef __attribute__((ext_vector_type(4))) unsigned short u16x4;
typedef __attribute__((ext_vector_type(4))) float f32x4;

constexpr int Bb = 4, Tt = 2048, Dd = 2048, Hh = 16, DHd = 128;

static __device__ __forceinline__ unsigned short f2bf(float f) {
  union { float f; unsigned u; } x; x.f = f;
  unsigned r = x.u + 0x7fffu + ((x.u >> 16) & 1u);
  return (unsigned short)(r >> 16);
}

// async global->LDS, 16B per lane (dest = wave-uniform base + lane*16)
static __device__ __forceinline__ void gld16(const void* g, void* l) {
  __builtin_amdgcn_global_load_lds(
      (__attribute__((address_space(1))) void*)g,
      (__attribute__((address_space(3))) void*)l, 16, 0, 0);
}

// ---------------------------------------------------------------------------
// fp32 -> bf16 bulk convert (8 elems/thread)
// ---------------------------------------------------------------------------
__global__ __launch_bounds__(256) void cvt_bf16(const float* __restrict__ s,
                                                unsigned short* __restrict__ d) {
  const size_t i = ((size_t)blockIdx.x * 256 + threadIdx.x) * 8;
  float4 a = *(const float4*)(s + i);
  float4 b = *(const float4*)(s + i + 4);
  bf16x8 pk;
  pk[0] = (short)f2bf(a.x); pk[1] = (short)f2bf(a.y);
  pk[2] = (short)f2bf(a.z); pk[3] = (short)f2bf(a.w);
  pk[4] = (short)f2bf(b.x); pk[5] = (short)f2bf(b.y);
  pk[6] = (short)f2bf(b.z); pk[7] = (short)f2bf(b.w);
  *(bf16x8*)(d + i) = pk;
}

// ---------------------------------------------------------------------------
// Weight transpose + fp32->bf16 convert: W[k][n] -> Wt[n][k]
// ---------------------------------------------------------------------------
__global__ __launch_bounds__(256) void wtrans_all(
    const float* __restrict__ Wq, const float* __restrict__ Wk,
    const float* __restrict__ Wv, const float* __restrict__ Wo,
    unsigned short* __restrict__ WqT, unsigned short* __restrict__ WkT,
    unsigned short* __restrict__ WvT, unsigned short* __restrict__ WoT,
    float qscale) {
  __shared__ __align__(16) unsigned short tile[64][72];
  const float* src;
  unsigned short* dst;
  float sc = 1.0f;
  switch (blockIdx.z) {
    case 0: src = Wq; dst = WqT; sc = qscale; break;
    case 1: src = Wk; dst = WkT; break;
    case 2: src = Wv; dst = WvT; break;
    default: src = Wo; dst = WoT; break;
  }
  const int t = threadIdx.x;
  const int k0 = blockIdx.x * 64, n0 = blockIdx.y * 64;
  const int c = t & 15, r = t >> 4;
#pragma unroll
  for (int p = 0; p < 4; ++p) {
    const int rr = r + 16 * p;
    float4 v = *(const float4*)(src + (size_t)(k0 + rr) * Dd + n0 + c * 4);
    u16x4 pk;
    pk[0] = f2bf(v.x * sc); pk[1] = f2bf(v.y * sc);
    pk[2] = f2bf(v.z * sc); pk[3] = f2bf(v.w * sc);
    *(u16x4*)&tile[rr][c * 4] = pk;
  }
  __syncthreads();
#pragma unroll
  for (int p = 0; p < 4; ++p) {
    const int nn = r + 16 * p;
    u16x4 pk;
    pk[0] = tile[c * 4 + 0][nn]; pk[1] = tile[c * 4 + 1][nn];
    pk[2] = tile[c * 4 + 2][nn]; pk[3] = tile[c * 4 + 3][nn];
    *(u16x4*)(dst + (size_t)(n0 + nn) * Dd + k0 + c * 4) = pk;
  }
}

// ---------------------------------------------------------------------------
// GEMM: out[8192][2048] = A[8192][2048](bf16) * Bt[2048][2048]^T (bf16)
// m97 structure: 128x128 tile, BK=64, global_load_lds width-16, linear LDS.
// OMODE: 0 = fp32 flat [M][N]; 1 = bf16 [B,H,T,dh]; 2 = bf16 [B,H,dh,T]
// ---------------------------------------------------------------------------
template <int OMODE>
__global__ __launch_bounds__(256, 2) void gemm_bt(
    const unsigned short* __restrict__ A, const unsigned short* __restrict__ Bt,
    void* __restrict__ Outp) {
  __shared__ __align__(16) unsigned short As[128 * 64];
  __shared__ __align__(16) unsigned short Bs[128 * 64];
  const int t = threadIdx.x;
  const int lane = t & 63, w = t >> 6;
  const int wr = w >> 1, wc = w & 1;
  const int fr = lane & 15, fq = lane >> 4;
  const int m0 = blockIdx.x * 128, n0 = blockIdx.y * 128;
  const int srow = t >> 3, scol = (t & 7) * 8;
  const unsigned short* Ag = A + (size_t)(m0 + srow) * Dd + scol;
  const unsigned short* Bg = Bt + (size_t)(n0 + srow) * Dd + scol;
  unsigned short* Asl = As + t * 8;
  unsigned short* Bsl = Bs + t * 8;

  f32x4 acc[4][4] = {};

  for (int k0 = 0; k0 < Dd; k0 += 64) {
#pragma unroll
    for (int i = 0; i < 4; ++i) {
      gld16(Ag + (size_t)i * 32 * Dd + k0, Asl + i * 2048);
      gld16(Bg + (size_t)i * 32 * Dd + k0, Bsl + i * 2048);
    }
    __syncthreads();
#pragma unroll
    for (int ks = 0; ks < 2; ++ks) {
      bf16x8 af[4], bfr[4];
#pragma unroll
      for (int m = 0; m < 4; ++m)
        af[m] = *(const bf16x8*)&As[(wr * 64 + m * 16 + fr) * 64 + ks * 32 + fq * 8];
#pragma unroll
      for (int n = 0; n < 4; ++n)
        bfr[n] = *(const bf16x8*)&Bs[(wc * 64 + n * 16 + fr) * 64 + ks * 32 + fq * 8];
#pragma unroll
      for (int m = 0; m < 4; ++m)
#pragma unroll
        for (int n = 0; n < 4; ++n)
          acc[m][n] = __builtin_amdgcn_mfma_f32_16x16x32_bf16(
              af[m], bfr[n], acc[m][n], 0, 0, 0);
    }
    __syncthreads();
  }

#pragma unroll
  for (int m = 0; m < 4; ++m) {
    const int mg = m0 + wr * 64 + m * 16 + fq * 4;
    const int bb = mg >> 11, tt0 = mg & (Tt - 1);
#pragma unroll
    for (int n = 0; n < 4; ++n) {
      const int ng = n0 + wc * 64 + n * 16 + fr;
      if (OMODE == 0) {
        float* o = (float*)Outp + (size_t)mg * Dd + ng;
#pragma unroll
        for (int r = 0; r < 4; ++r) o[(size_t)r * Dd] = acc[m][n][r];
      } else if (OMODE == 1) {
        const int h = ng >> 7, dh = ng & 127;
        unsigned short* o = (unsigned short*)Outp +
                            (((size_t)bb * Hh + h) * Tt + tt0) * DHd + dh;
#pragma unroll
        for (int r = 0; r < 4; ++r) o[r * DHd] = f2bf(acc[m][n][r]);
      } else {
        const int h = ng >> 7, dh = ng & 127;
        u16x4 pk;
#pragma unroll
        for (int r = 0; r < 4; ++r) pk[r] = f2bf(acc[m][n][r]);
        *(u16x4*)((unsigned short*)Outp +
                  (((size_t)bb * Hh + h) * DHd + dh) * Tt + tt0) = pk;
      }
    }
  }
}

// ---------------------------------------------------------------------------
// Causal flash attention. QBLK=128 (8 waves x 16 q-rows), KVBLK=64.
// XCD-swizzled 1-D grid: all 16 q-blocks of a head land on one XCD -> that
// XCD's L2 fetches the head's K/V (1 MB) from HBM once. K/V double-buffered
// in LDS (64 KB total -> 2 blocks/CU = 16 waves/CU) via global_load_lds,
// counted vmcnt(4). LDS XOR-swizzled (chunk ^= row&7) via pre-swizzled
// global source. S^T = mfma(K,Q): per-lane scalar softmax (q=fr), exp2
// domain, defer-max. P redistribution for PV is fully in-register (shfl).
// Q,K: [B,H,T,128] bf16; V: [B,H,128,T] bf16; Out: [B,T,2048] bf16.
// ---------------------------------------------------------------------------
__global__ __launch_bounds__(512, 4) void fattn(
    const unsigned short* __restrict__ Qp, const unsigned short* __restrict__ Kp,
    const unsigned short* __restrict__ Vt, unsigned short* __restrict__ Ao) {
  __shared__ __align__(16) unsigned short Ks[2][64 * 128];  // K[kv][dh], swizzled
  __shared__ __align__(16) unsigned short Vs[2][128 * 64];  // V^T[dv][kv], swizzled
  const int t = threadIdx.x, lane = t & 63, w = t >> 6;
  const int fr = lane & 15, fq = lane >> 4;
  const int rsw = fr & 7;
  // XCD swizzle: id -> (xcd, head, qb); 16 q-blocks of a head share one XCD.
  const int id = blockIdx.x;            // 1024 blocks
  const int xcd = id & 7, slot = id >> 3;
  const int bh = xcd * 8 + (slot >> 4);
  const int qb = 15 - (slot & 15);      // heaviest blocks dispatched first
  const int q0w = qb * 128 + w * 16;    // this wave's 16 q-rows
  const unsigned short* Qb = Qp + (size_t)bh * Tt * DHd;
  const unsigned short* Kb = Kp + (size_t)bh * Tt * DHd;
  const unsigned short* Vb = Vt + (size_t)bh * DHd * Tt;

  bf16x8 qf[4];
#pragma unroll
  for (int ks = 0; ks < 4; ++ks)
    qf[ks] = *(const bf16x8*)(Qb + (size_t)(q0w + fr) * DHd + ks * 32 + fq * 8);

  f32x4 oacc[8] = {};
  float m_ = -1e30f, l_ = 0.f;

  // stage tile kv0 into buffer b; global source chunk pre-swizzled (^ row&7)
  auto STAGE = [&](int b, int kv0) {
#pragma unroll
    for (int p = 0; p < 2; ++p) {  // K: 64 rows x 16 chunks of 16B
      const int idx = t + p * 512, row = idx >> 4, ch = idx & 15;
      gld16(Kb + (size_t)(kv0 + row) * DHd + ((ch ^ (row & 7)) * 8),
            &Ks[b][idx * 8]);
    }
#pragma unroll
    for (int p = 0; p < 2; ++p) {  // V: 128 rows x 8 chunks of 16B
      const int idx = t + p * 512, row = idx >> 3, ch = idx & 7;
      gld16(Vb + (size_t)row * Tt + kv0 + ((ch ^ (row & 7)) * 8),
            &Vs[b][idx * 8]);
    }
  };

  const int ntile = 2 * qb + 2;
  STAGE(0, 0);
  int cur = 0;

  for (int kt = 0; kt < ntile; ++kt) {
    const int kv0 = kt * 64;
    __builtin_amdgcn_s_barrier();  // all waves done reading buf[cur^1]
    if (kt + 1 < ntile) {
      STAGE(cur ^ 1, (kt + 1) * 64);
      asm volatile("s_waitcnt vmcnt(4)" ::: "memory");  // tile kt's 4 landed
    } else {
      asm volatile("s_waitcnt vmcnt(0)" ::: "memory");
    }
    __builtin_amdgcn_sched_barrier(0);
    __builtin_amdgcn_s_barrier();  // buf[cur] visible to all waves

    if (kv0 <= q0w + 15) {  // skip fully-masked tiles (wave-uniform)
      const unsigned short* Kc = &Ks[cur][0];
      const unsigned short* Vc = &Vs[cur][0];

      // S^T = K.Q^T : lane holds S[kv = tt*16+fq*4+r][q = fr]
      f32x4 s[4] = {};
      __builtin_amdgcn_s_setprio(1);
#pragma unroll
      for (int tt = 0; tt < 4; ++tt) {
        bf16x8 kf[4];
#pragma unroll
        for (int ks = 0; ks < 4; ++ks)
          kf[ks] = *(const bf16x8*)(Kc + (tt * 16 + fr) * 128 +
                                    ((ks * 4 + fq) ^ rsw) * 8);
#pragma unroll
        for (int ks = 0; ks < 4; ++ks)
          s[tt] = __builtin_amdgcn_mfma_f32_16x16x32_bf16(kf[ks], qf[ks], s[tt], 0, 0, 0);
      }
      __builtin_amdgcn_s_setprio(0);

      if (kv0 + 63 > q0w) {  // diagonal region: causal mask
        const int qa = q0w + fr;
#pragma unroll
        for (int tt = 0; tt < 4; ++tt)
#pragma unroll
          for (int r = 0; r < 4; ++r)
            if (kv0 + tt * 16 + fq * 4 + r > qa) s[tt][r] = -1e30f;
      }

      // online softmax in exp2 domain, per-lane scalar state (q = fr)
      float tmax = s[0][0];
#pragma unroll
      for (int tt = 0; tt < 4; ++tt)
#pragma unroll
        for (int r = 0; r < 4; ++r) tmax = fmaxf(tmax, s[tt][r]);
      tmax = fmaxf(tmax, __shfl_xor(tmax, 16));
      tmax = fmaxf(tmax, __shfl_xor(tmax, 32));

      if (!__all(tmax <= m_ + 8.0f)) {  // defer-max: rescale only on growth
        const float mn = fmaxf(m_, tmax);
        const float alpha = __builtin_amdgcn_exp2f(m_ - mn);
        m_ = mn;
        float al4[4];
#pragma unroll
        for (int r = 0; r < 4; ++r) al4[r] = __shfl(alpha, fq * 4 + r);
#pragma unroll
        for (int dt = 0; dt < 8; ++dt)
#pragma unroll
          for (int r = 0; r < 4; ++r) oacc[dt][r] *= al4[r];
        l_ *= alpha;
      }

      float rs = 0.f;
#pragma unroll
      for (int tt = 0; tt < 4; ++tt)
#pragma unroll
        for (int r = 0; r < 4; ++r) {
          const float p = __builtin_amdgcn_exp2f(s[tt][r] - m_);
          s[tt][r] = p;
          rs += p;
        }
      rs += __shfl_xor(rs, 16);
      rs += __shfl_xor(rs, 32);
      l_ += rs;

      // pack P rows to bf16 pairs: c[tt] = {bf16(s0,s1), bf16(s2,s3)}
      uint2 c[4];
#pragma unroll
      for (int tt = 0; tt < 4; ++tt) {
        unsigned r0, r1;
        asm("v_cvt_pk_bf16_f32 %0, %1, %2" : "=v"(r0) : "v"(s[tt][0]), "v"(s[tt][1]));
        asm("v_cvt_pk_bf16_f32 %0, %1, %2" : "=v"(r1) : "v"(s[tt][2]), "v"(s[tt][3]));
        c[tt].x = r0; c[tt].y = r1;
      }

      // in-register P redistribution: pf word j = word (j&1) of source lane
      // (fr + 16*(2(fq&1)+(j>>1)))'s c[2*ks2 + (fq>>1)]
      const int src0 = fr + 32 * (fq & 1);
      const int src1 = src0 + 16;
      const bool hi = (fq >> 1) != 0;
      __builtin_amdgcn_s_setprio(1);
#pragma unroll
      for (int ks2 = 0; ks2 < 2; ++ks2) {
        const int a0 = __shfl((int)c[2 * ks2].x, src0);
        const int b0 = __shfl((int)c[2 * ks2 + 1].x, src0);
        const int a1 = __shfl((int)c[2 * ks2].y, src0);
        const int b1 = __shfl((int)c[2 * ks2 + 1].y, src0);
        const int a2 = __shfl((int)c[2 * ks2].x, src1);
        const int b2 = __shfl((int)c[2 * ks2 + 1].x, src1);
        const int a3 = __shfl((int)c[2 * ks2].y, src1);
        const int b3 = __shfl((int)c[2 * ks2 + 1].y, src1);
        union { int wd[4]; bf16x8 v; } pf;
        pf.wd[0] = hi ? b0 : a0;
        pf.wd[1] = hi ? b1 : a1;
        pf.wd[2] = hi ? b2 : a2;
        pf.wd[3] = hi ? b3 : a3;
#pragma unroll
        for (int dt = 0; dt < 8; ++dt) {
          const bf16x8 vf = *(const bf16x8*)(Vc + (dt * 16 + fr) * 64 +
                                             ((ks2 * 4 + fq) ^ rsw) * 8);
          oacc[dt] = __builtin_amdgcn_mfma_f32_16x16x32_bf16(pf.v, vf, oacc[dt], 0, 0, 0);
        }
      }
      __builtin_amdgcn_s_setprio(0);
    }
    cur ^= 1;
  }

  const int bb = bh >> 4, hh = bh & 15;
  float linv[4];
#pragma unroll
  for (int r = 0; r < 4; ++r) linv[r] = 1.0f / __shfl(l_, fq * 4 + r);
  const int qrow = q0w + fq * 4;
#pragma unroll
  for (int r = 0; r < 4; ++r) {
    unsigned short* o = Ao + ((size_t)bb * Tt + qrow + r) * Dd + hh * DHd + fr;
#pragma unroll
    for (int dt = 0; dt < 8; ++dt) o[dt * 16] = f2bf(oacc[dt][r] * linv[r]);
  }
}

// ---------------------------------------------------------------------------
extern "C" void kernel_launch(void* const* d_in, const int* in_sizes, int n_in,
                              void* d_out, int out_size, void* d_ws, size_t ws_size,
                              hipStream_t stream) {
  const float* q = (const float*)d_in[0];
  const float* k = (const float*)d_in[1];
  const float* v = (const float*)d_in[2];
  // d_in[3] = mask (known causal tril; unused)
  const float* Wq = (const float*)d_in[4];
  const float* Wk = (const float*)d_in[5];
  const float* Wv = (const float*)d_in[6];
  const float* Wo = (const float*)d_in[7];

  const size_t WE = (size_t)Dd * Dd;
  const size_t PE = (size_t)Bb * Hh * Tt * DHd;
  unsigned short* WqT = (unsigned short*)d_ws;
  unsigned short* WkT = WqT + WE;
  unsigned short* WvT = WkT + WE;
  unsigned short* WoT = WvT + WE;
  unsigned short* Qx = WoT + WE;  // [B,H,T,dh]
  unsigned short* Kx = Qx + PE;   // [B,H,T,dh]
  unsigned short* Vx = Kx + PE;   // [B,H,dh,T]
  unsigned short* Ax = Vx + PE;   // bf16 staging, then attn out [B,T,H*dh]

  // scores in exp2 domain: fold log2(e)/sqrt(dk) into Wq
  const float qscale = (float)(1.4426950408889634 / 11.313708498984761);
  wtrans_all<<<dim3(32, 32, 4), 256, 0, stream>>>(
      Wq, Wk, Wv, Wo, WqT, WkT, WvT, WoT, qscale);

  cvt_bf16<<<dim3(8192), 256, 0, stream>>>(q, Ax);
  gemm_bt<1><<<dim3(64, 16), 256, 0, stream>>>(Ax, WqT, Qx);
  cvt_bf16<<<dim3(8192), 256, 0, stream>>>(k, Ax);
  gemm_bt<1><<<dim3(64, 16), 256, 0, stream>>>(Ax, WkT, Kx);
  cvt_bf16<<<dim3(8192), 256, 0, stream>>>(v, Ax);
  gemm_bt<2><<<dim3(64, 16), 256, 0, stream>>>(Ax, WvT, Vx);
  fattn<<<dim3(1024), 512, 0, stream>>>(Qx, Kx, Vx, Ax);
  gemm_bt<0><<<dim3(64, 16), 256, 0, stream>>>(Ax, WoT, (float*)d_out);
}